// Round 3
// baseline (1732.083 us; speedup 1.0000x reference)
//
#include <hip/hip_runtime.h>

using u16 = unsigned short;
using u32 = unsigned int;

typedef __attribute__((ext_vector_type(8))) __bf16 bf16x8;
typedef __attribute__((ext_vector_type(4))) float f32x4;

__device__ __forceinline__ u16 f2bf(float f) {
  u32 u = __float_as_uint(f);
  u32 r = (u + 0x7fffu + ((u >> 16) & 1u)) >> 16;  // RNE
  return (u16)r;
}
__device__ __forceinline__ u32 pk2(float a, float b) {
  return (u32)f2bf(a) | ((u32)f2bf(b) << 16);
}
__device__ __forceinline__ float bf2f(u16 h) {
  return __uint_as_float(((u32)h) << 16);
}
__device__ __forceinline__ void gload16(const u16* g, u16* l) {
  __builtin_amdgcn_global_load_lds((const __attribute__((address_space(1))) void*)g,
                                   (__attribute__((address_space(3))) void*)l, 16, 0, 0);
}
__device__ __forceinline__ f32x4 mfma_bf16(bf16x8 a, bf16x8 b, f32x4 c) {
  return __builtin_amdgcn_mfma_f32_16x16x32_bf16(a, b, c, 0, 0, 0);
}

// ---------------- fp32 -> bf16 convert ----------------
__global__ __launch_bounds__(256) void cvt_bf16(const float* __restrict__ in,
                                                u16* __restrict__ out, int n8) {
  int i = blockIdx.x * 256 + threadIdx.x;
  int stride = gridDim.x * 256;
  for (; i < n8; i += stride) {
    float4 a = ((const float4*)in)[(size_t)i * 2];
    float4 b = ((const float4*)in)[(size_t)i * 2 + 1];
    ((uint4*)out)[i] = make_uint4(pk2(a.x, a.y), pk2(a.z, a.w), pk2(b.x, b.y), pk2(b.z, b.w));
  }
}

// ---------------- RMSNorm (H=2048), fp32 in -> bf16 out ----------------
__global__ __launch_bounds__(256) void rmsnorm_bf16(const float* __restrict__ x,
                                                    const float* __restrict__ g,
                                                    u16* __restrict__ o) {
  const int row = blockIdx.x;
  const int tid = threadIdx.x;
  const float4* xr = (const float4*)(x + (size_t)row * 2048);
  float4 a = xr[tid * 2], b = xr[tid * 2 + 1];
  float s = a.x * a.x + a.y * a.y + a.z * a.z + a.w * a.w +
            b.x * b.x + b.y * b.y + b.z * b.z + b.w * b.w;
#pragma unroll
  for (int off = 1; off < 64; off <<= 1) s += __shfl_xor(s, off);
  __shared__ float red[4];
  if ((tid & 63) == 0) red[tid >> 6] = s;
  __syncthreads();
  s = red[0] + red[1] + red[2] + red[3];
  const float r = rsqrtf(s * (1.0f / 2048.0f) + 1.1920929e-07f);
  const float4* gr = (const float4*)g;
  float4 ga = gr[tid * 2], gb = gr[tid * 2 + 1];
  ((uint4*)(o + (size_t)row * 2048))[tid] =
      make_uint4(pk2(a.x * r * ga.x, a.y * r * ga.y), pk2(a.z * r * ga.z, a.w * r * ga.w),
                 pk2(b.x * r * gb.x, b.y * r * gb.y), pk2(b.z * r * gb.z, b.w * r * gb.w));
}

// ---------------- GEMM: C[M,N] = A[M,K] @ B[N,K]^T  (m97 structure) ----------------
// EPI=0: Cb = bf16(acc).  EPI=1: Cf = Res + acc (fp32, may alias).
// EPI=2: Cb = bf16( silu(Cb) * acc )   (fused gate*up)
// BT = u16 (bf16 weights) or float (on-the-fly convert).
template <int EPI, typename BT>
__global__ __launch_bounds__(256) void gemm_bt(const u16* __restrict__ A,
                                               const BT* __restrict__ B,
                                               u16* Cb, float* Cf, const float* Res,
                                               int M, int N, int K) {
  alignas(16) __shared__ u16 As[128 * 32];
  alignas(16) __shared__ u16 Bs[128 * 32];
  const int tid = threadIdx.x;
  const int w = tid >> 6, lane = tid & 63;
  const int lo = lane & 15, hi = lane >> 4;
  const int bm = blockIdx.y * 128, bn = blockIdx.x * 128;
  const int wr = (w >> 1) * 64, wc = (w & 1) * 64;

  f32x4 acc[4][4] = {};

  const int r0 = tid >> 2;        // staged row 0..63
  const int kc0 = (tid & 3) * 8;  // k-offset within 32
  const u16* a0 = A + (size_t)(bm + r0) * K + kc0;
  const u16* a1 = A + (size_t)(bm + 64 + r0) * K + kc0;
  const BT* b0 = B + (size_t)(bn + r0) * K + kc0;
  const BT* b1 = B + (size_t)(bn + 64 + r0) * K + kc0;
  u16* asd0 = &As[(size_t)tid * 8];
  u16* asd1 = &As[(size_t)(tid + 256) * 8];
  u16* bsd0 = &Bs[(size_t)tid * 8];
  u16* bsd1 = &Bs[(size_t)(tid + 256) * 8];

  for (int kt = 0; kt < K; kt += 32) {
    gload16(a0 + kt, asd0);
    gload16(a1 + kt, asd1);
    if constexpr (sizeof(BT) == 2) {
      gload16((const u16*)(b0 + kt), bsd0);
      gload16((const u16*)(b1 + kt), bsd1);
    } else {
      float4 x0 = *(const float4*)(b0 + kt);
      float4 x1 = *(const float4*)(b0 + kt + 4);
      float4 y0 = *(const float4*)(b1 + kt);
      float4 y1 = *(const float4*)(b1 + kt + 4);
      *(uint4*)bsd0 = make_uint4(pk2(x0.x, x0.y), pk2(x0.z, x0.w), pk2(x1.x, x1.y), pk2(x1.z, x1.w));
      *(uint4*)bsd1 = make_uint4(pk2(y0.x, y0.y), pk2(y0.z, y0.w), pk2(y1.x, y1.y), pk2(y1.z, y1.w));
    }
    __syncthreads();  // drains vmcnt+lgkmcnt -> LDS tiles valid
    bf16x8 af[4], bfr[4];
#pragma unroll
    for (int i = 0; i < 4; ++i) {
      af[i] = *(const bf16x8*)(&As[(wr + i * 16 + lo) * 32 + hi * 8]);
      bfr[i] = *(const bf16x8*)(&Bs[(wc + i * 16 + lo) * 32 + hi * 8]);
    }
#pragma unroll
    for (int i = 0; i < 4; ++i)
#pragma unroll
      for (int j = 0; j < 4; ++j) acc[i][j] = mfma_bf16(af[i], bfr[j], acc[i][j]);
    __syncthreads();  // protect LDS before next stage
  }

#pragma unroll
  for (int i = 0; i < 4; ++i) {
    const int gr = bm + wr + i * 16 + hi * 4;
#pragma unroll
    for (int j = 0; j < 4; ++j) {
      const int gc = bn + wc + j * 16 + lo;
#pragma unroll
      for (int r = 0; r < 4; ++r) {
        const size_t idx = (size_t)(gr + r) * N + gc;
        if constexpr (EPI == 1) {
          Cf[idx] = Res[idx] + acc[i][j][r];
        } else if constexpr (EPI == 2) {
          float g = bf2f(Cb[idx]);
          float s = g / (1.f + __expf(-g));
          Cb[idx] = f2bf(s * acc[i][j][r]);
        } else {
          Cb[idx] = f2bf(acc[i][j][r]);
        }
      }
    }
  }
}

// ---------------- V transpose: v[B,S,NH,HD] -> vt[B,NH,HD,S] ----------------
__global__ __launch_bounds__(256) void transpose_v(const u16* __restrict__ v,
                                                   u16* __restrict__ vt) {
  __shared__ u16 t[32][33];
  const int bh = blockIdx.z, b = bh >> 4, h = bh & 15;
  const int s0 = blockIdx.x * 32, d0 = blockIdx.y * 32;
  const int tx = threadIdx.x, ty = threadIdx.y;
#pragma unroll
  for (int i = 0; i < 4; ++i)
    t[ty + i * 8][tx] = v[(size_t)(b * 2048 + s0 + ty + i * 8) * 2048 + h * 128 + d0 + tx];
  __syncthreads();
#pragma unroll
  for (int i = 0; i < 4; ++i)
    vt[(size_t)(bh * 128 + d0 + ty + i * 8) * 2048 + s0 + tx] = t[tx][ty + i * 8];
}

// ---------------- flash attention fwd (bf16, online softmax) ----------------
// grid: (S/64, B*NH), block 256 = 4 independent waves, 16 q-rows each.
// o may alias q: each block reads only its own q rows (into regs) before writing them.
__global__ __launch_bounds__(256) void attn_fwd(const u16* __restrict__ q,
                                                const u16* __restrict__ k,
                                                const u16* __restrict__ vt,
                                                u16* o) {
  constexpr int S = 2048, HH = 2048;
  const int bh = blockIdx.y, b = bh >> 4, h = bh & 15;
  const int tid = threadIdx.x, w = tid >> 6, lane = tid & 63;
  const int lo = lane & 15, hi = lane >> 4;
  const int qr = blockIdx.x * 64 + w * 16;

  alignas(16) __shared__ u16 plds[4][16 * 72];
  u16* pl = &plds[w][0];

  bf16x8 qf[4];
  const u16* qb = q + (size_t)(b * S + qr + lo) * HH + h * 128 + hi * 8;
#pragma unroll
  for (int ks = 0; ks < 4; ++ks) qf[ks] = *(const bf16x8*)(qb + ks * 32);

  f32x4 oacc[8] = {};
  float m[4], l[4];
#pragma unroll
  for (int r = 0; r < 4; ++r) { m[r] = -1e30f; l[r] = 0.f; }

  const u16* kb = k + (size_t)(b * S) * HH + h * 128;
  const u16* vb = vt + (size_t)bh * 128 * S;

  for (int kv = 0; kv < S; kv += 64) {
    f32x4 sacc[4] = {};
#pragma unroll
    for (int ks = 0; ks < 4; ++ks)
#pragma unroll
      for (int n = 0; n < 4; ++n) {
        bf16x8 kf = *(const bf16x8*)(kb + (size_t)(kv + n * 16 + lo) * HH + ks * 32 + hi * 8);
        sacc[n] = mfma_bf16(qf[ks], kf, sacc[n]);
      }
    constexpr float sc = 0.08838834764831845f;  // 1/sqrt(128)
    constexpr float L2E = 1.4426950408889634f;
#pragma unroll
    for (int n = 0; n < 4; ++n) sacc[n] = sacc[n] * sc;
    float mv[4];
#pragma unroll
    for (int r = 0; r < 4; ++r)
      mv[r] = fmaxf(fmaxf(sacc[0][r], sacc[1][r]), fmaxf(sacc[2][r], sacc[3][r]));
#pragma unroll
    for (int off = 1; off < 16; off <<= 1)
#pragma unroll
      for (int r = 0; r < 4; ++r) mv[r] = fmaxf(mv[r], __shfl_xor(mv[r], off));
    float corr[4];
#pragma unroll
    for (int r = 0; r < 4; ++r) {
      float mn = fmaxf(m[r], mv[r]);
      corr[r] = exp2f((m[r] - mn) * L2E);
      m[r] = mn;
    }
    f32x4 p[4];
#pragma unroll
    for (int n = 0; n < 4; ++n)
#pragma unroll
      for (int r = 0; r < 4; ++r) p[n][r] = exp2f((sacc[n][r] - m[r]) * L2E);
    float ps[4];
#pragma unroll
    for (int r = 0; r < 4; ++r) ps[r] = p[0][r] + p[1][r] + p[2][r] + p[3][r];
#pragma unroll
    for (int off = 1; off < 16; off <<= 1)
#pragma unroll
      for (int r = 0; r < 4; ++r) ps[r] += __shfl_xor(ps[r], off);
#pragma unroll
    for (int r = 0; r < 4; ++r) l[r] = l[r] * corr[r] + ps[r];
#pragma unroll
    for (int f = 0; f < 8; ++f)
#pragma unroll
      for (int r = 0; r < 4; ++r) oacc[f][r] *= corr[r];
    // P (16x64) -> LDS, then reread in A-frag layout
#pragma unroll
    for (int n = 0; n < 4; ++n)
#pragma unroll
      for (int r = 0; r < 4; ++r)
        pl[(hi * 4 + r) * 72 + n * 16 + lo] = f2bf(p[n][r]);
    asm volatile("s_waitcnt lgkmcnt(0)" ::: "memory");
    bf16x8 pf0 = *(const bf16x8*)(pl + lo * 72 + hi * 8);
    bf16x8 pf1 = *(const bf16x8*)(pl + lo * 72 + 32 + hi * 8);
#pragma unroll
    for (int f = 0; f < 8; ++f) {
      const u16* vr = vb + (size_t)(f * 16 + lo) * S + kv + hi * 8;
      bf16x8 vf0 = *(const bf16x8*)(vr);
      bf16x8 vf1 = *(const bf16x8*)(vr + 32);
      oacc[f] = mfma_bf16(pf0, vf0, oacc[f]);
      oacc[f] = mfma_bf16(pf1, vf1, oacc[f]);
    }
  }
  u16* ob = o + (size_t)(b * S + qr) * HH + h * 128;
#pragma unroll
  for (int f = 0; f < 8; ++f)
#pragma unroll
    for (int r = 0; r < 4; ++r)
      ob[(size_t)(hi * 4 + r) * HH + f * 16 + lo] = f2bf(oacc[f][r] / l[r]);
}

// ---------------- host ----------------
extern "C" void kernel_launch(void* const* d_in, const int* in_sizes, int n_in,
                              void* d_out, int out_size, void* d_ws, size_t ws_size,
                              hipStream_t stream) {
  constexpr int B = 2, S = 2048, H = 2048, NH = 16, I = 8192;
  constexpr int M = B * S;   // 4096
  constexpr int MC = 2048;   // MLP M-chunk

  const float* hs = (const float*)d_in[0];
  const float* Wq = (const float*)d_in[1];
  const float* Wk = (const float*)d_in[2];
  const float* Wv = (const float*)d_in[3];
  const float* Wo = (const float*)d_in[4];
  const float* Wg = (const float*)d_in[5];
  const float* Wu = (const float*)d_in[6];
  const float* Wd = (const float*)d_in[7];
  const float* g_in = (const float*)d_in[8];
  const float* g_post = (const float*)d_in[9];
  float* out = (float*)d_out;

  constexpr size_t SZ_HH = (size_t)H * H * 2;  // 8 MiB
  constexpr size_t SZ_IH = (size_t)I * H * 2;  // 32 MiB
  constexpr size_t SZ_MH = (size_t)M * H * 2;  // 16 MiB
  constexpr size_t NEED_MIN = 5 * SZ_MH;                          // 80 MiB
  constexpr size_t NEED_FULL = NEED_MIN + 4 * SZ_HH + 3 * SZ_IH;  // 208 MiB

  char* p = (char*)d_ws;
  u16* x_b = (u16*)p;   p += SZ_MH;
  u16* q_b = (u16*)p;   p += SZ_MH;   // also attention output (in-place)
  u16* k_b = (u16*)p;   p += SZ_MH;
  u16* v_b = (u16*)p;   p += SZ_MH;
  u16* vt_b = (u16*)p;  p += SZ_MH;
  u16* g_mlp = k_b;  // 32 MiB gate chunk reuses dead K+V after attention
  const bool fast = ws_size >= NEED_FULL;
  u16 *wq_b = nullptr, *wk_b = nullptr, *wv_b = nullptr, *wo_b = nullptr,
      *wg_b = nullptr, *wu_b = nullptr, *wd_b = nullptr;
  if (fast) {
    wq_b = (u16*)p; p += SZ_HH;
    wk_b = (u16*)p; p += SZ_HH;
    wv_b = (u16*)p; p += SZ_HH;
    wo_b = (u16*)p; p += SZ_HH;
    wg_b = (u16*)p; p += SZ_IH;
    wu_b = (u16*)p; p += SZ_IH;
    wd_b = (u16*)p; p += SZ_IH;
    cvt_bf16<<<1024, 256, 0, stream>>>(Wq, wq_b, H * H / 8);
    cvt_bf16<<<1024, 256, 0, stream>>>(Wk, wk_b, H * H / 8);
    cvt_bf16<<<1024, 256, 0, stream>>>(Wv, wv_b, H * H / 8);
    cvt_bf16<<<1024, 256, 0, stream>>>(Wo, wo_b, H * H / 8);
    cvt_bf16<<<1024, 256, 0, stream>>>(Wg, wg_b, I * H / 8);
    cvt_bf16<<<1024, 256, 0, stream>>>(Wu, wu_b, I * H / 8);
    cvt_bf16<<<1024, 256, 0, stream>>>(Wd, wd_b, I * H / 8);
  }

  // x = rmsnorm(hidden, g_in)
  rmsnorm_bf16<<<M, 256, 0, stream>>>(hs, g_in, x_b);

  // Q/K/V projections
  const dim3 gHH(H / 128, M / 128);
  if (fast) {
    gemm_bt<0, u16><<<gHH, 256, 0, stream>>>(x_b, wq_b, q_b, nullptr, nullptr, M, H, H);
    gemm_bt<0, u16><<<gHH, 256, 0, stream>>>(x_b, wk_b, k_b, nullptr, nullptr, M, H, H);
    gemm_bt<0, u16><<<gHH, 256, 0, stream>>>(x_b, wv_b, v_b, nullptr, nullptr, M, H, H);
  } else {
    gemm_bt<0, float><<<gHH, 256, 0, stream>>>(x_b, Wq, q_b, nullptr, nullptr, M, H, H);
    gemm_bt<0, float><<<gHH, 256, 0, stream>>>(x_b, Wk, k_b, nullptr, nullptr, M, H, H);
    gemm_bt<0, float><<<gHH, 256, 0, stream>>>(x_b, Wv, v_b, nullptr, nullptr, M, H, H);
  }

  // V -> Vt per head, then attention (output in-place into q_b)
  transpose_v<<<dim3(S / 32, 128 / 32, B * NH), dim3(32, 8), 0, stream>>>(v_b, vt_b);
  attn_fwd<<<dim3(S / 64, B * NH), 256, 0, stream>>>(q_b, k_b, vt_b, q_b);

  // hidden2 = residual + attn @ Wo^T   (fp32, into d_out)
  if (fast)
    gemm_bt<1, u16><<<gHH, 256, 0, stream>>>(q_b, wo_b, nullptr, out, hs, M, H, H);
  else
    gemm_bt<1, float><<<gHH, 256, 0, stream>>>(q_b, Wo, nullptr, out, hs, M, H, H);

  // x2 = rmsnorm(hidden2, g_post)
  rmsnorm_bf16<<<M, 256, 0, stream>>>(out, g_post, x_b);

  // MLP, chunked over M so gate fits in 32 MiB
  const dim3 gIH(I / 128, MC / 128), gHI(H / 128, MC / 128);
  for (int mc = 0; mc < M / MC; ++mc) {
    const u16* xc = x_b + (size_t)mc * MC * H;
    float* oc = out + (size_t)mc * MC * H;
    if (fast) {
      gemm_bt<0, u16><<<gIH, 256, 0, stream>>>(xc, wg_b, g_mlp, nullptr, nullptr, MC, I, H);
      gemm_bt<2, u16><<<gIH, 256, 0, stream>>>(xc, wu_b, g_mlp, nullptr, nullptr, MC, I, H);
      gemm_bt<1, u16><<<gHI, 256, 0, stream>>>(g_mlp, wd_b, nullptr, oc, oc, MC, H, I);
    } else {
      gemm_bt<0, float><<<gIH, 256, 0, stream>>>(xc, Wg, g_mlp, nullptr, nullptr, MC, I, H);
      gemm_bt<2, float><<<gIH, 256, 0, stream>>>(xc, Wu, g_mlp, nullptr, nullptr, MC, I, H);
      gemm_bt<1, float><<<gHI, 256, 0, stream>>>(g_mlp, Wd, nullptr, oc, oc, MC, H, I);
    }
  }
}

// Round 4
// 1390.383 us; speedup vs baseline: 1.2458x; 1.2458x over previous
//
#include <hip/hip_runtime.h>

using u16 = unsigned short;
using u32 = unsigned int;

typedef __attribute__((ext_vector_type(8))) __bf16 bf16x8;
typedef __attribute__((ext_vector_type(4))) float f32x4;

__device__ __forceinline__ u16 f2bf(float f) {
  u32 u = __float_as_uint(f);
  u32 r = (u + 0x7fffu + ((u >> 16) & 1u)) >> 16;  // RNE
  return (u16)r;
}
__device__ __forceinline__ u32 pk2(float a, float b) {
  return (u32)f2bf(a) | ((u32)f2bf(b) << 16);
}
__device__ __forceinline__ float bf2f(u16 h) {
  return __uint_as_float(((u32)h) << 16);
}
__device__ __forceinline__ void gload16(const u16* g, u16* l) {
  __builtin_amdgcn_global_load_lds((const __attribute__((address_space(1))) void*)g,
                                   (__attribute__((address_space(3))) void*)l, 16, 0, 0);
}
__device__ __forceinline__ f32x4 mfma_bf16(bf16x8 a, bf16x8 b, f32x4 c) {
  return __builtin_amdgcn_mfma_f32_16x16x32_bf16(a, b, c, 0, 0, 0);
}

// ---------------- fp32 -> bf16 convert ----------------
__global__ __launch_bounds__(256) void cvt_bf16(const float* __restrict__ in,
                                                u16* __restrict__ out, int n8) {
  int i = blockIdx.x * 256 + threadIdx.x;
  int stride = gridDim.x * 256;
  for (; i < n8; i += stride) {
    float4 a = ((const float4*)in)[(size_t)i * 2];
    float4 b = ((const float4*)in)[(size_t)i * 2 + 1];
    ((uint4*)out)[i] = make_uint4(pk2(a.x, a.y), pk2(a.z, a.w), pk2(b.x, b.y), pk2(b.z, b.w));
  }
}

// ---------------- RMSNorm (H=2048), fp32 in -> bf16 out ----------------
__global__ __launch_bounds__(256) void rmsnorm_bf16(const float* __restrict__ x,
                                                    const float* __restrict__ g,
                                                    u16* __restrict__ o) {
  const int row = blockIdx.x;
  const int tid = threadIdx.x;
  const float4* xr = (const float4*)(x + (size_t)row * 2048);
  float4 a = xr[tid * 2], b = xr[tid * 2 + 1];
  float s = a.x * a.x + a.y * a.y + a.z * a.z + a.w * a.w +
            b.x * b.x + b.y * b.y + b.z * b.z + b.w * b.w;
#pragma unroll
  for (int off = 1; off < 64; off <<= 1) s += __shfl_xor(s, off);
  __shared__ float red[4];
  if ((tid & 63) == 0) red[tid >> 6] = s;
  __syncthreads();
  s = red[0] + red[1] + red[2] + red[3];
  const float r = rsqrtf(s * (1.0f / 2048.0f) + 1.1920929e-07f);
  const float4* gr = (const float4*)g;
  float4 ga = gr[tid * 2], gb = gr[tid * 2 + 1];
  ((uint4*)(o + (size_t)row * 2048))[tid] =
      make_uint4(pk2(a.x * r * ga.x, a.y * r * ga.y), pk2(a.z * r * ga.z, a.w * r * ga.w),
                 pk2(b.x * r * gb.x, b.y * r * gb.y), pk2(b.z * r * gb.z, b.w * r * gb.w));
}

// ---------------- GEMM: C[M,N] = A[M,K] @ B[N,K]^T  (m97 structure) ----------------
// EPI=0: Cb = bf16(acc).  EPI=1: Cf = Res + acc (fp32, may alias).
// EPI=2: Cb = bf16( silu(Cb) * acc )   (fused gate*up)
// BT = u16 (bf16 weights) or float (on-the-fly convert).
template <int EPI, typename BT>
__global__ __launch_bounds__(256) void gemm_bt(const u16* __restrict__ A,
                                               const BT* __restrict__ B,
                                               u16* Cb, float* Cf, const float* Res,
                                               int M, int N, int K) {
  alignas(16) __shared__ u16 As[128 * 32];
  alignas(16) __shared__ u16 Bs[128 * 32];
  const int tid = threadIdx.x;
  const int w = tid >> 6, lane = tid & 63;
  const int lo = lane & 15, hi = lane >> 4;
  const int bm = blockIdx.y * 128, bn = blockIdx.x * 128;
  const int wr = (w >> 1) * 64, wc = (w & 1) * 64;

  f32x4 acc[4][4] = {};

  const int r0 = tid >> 2;        // staged row 0..63
  const int kc0 = (tid & 3) * 8;  // k-offset within 32
  const u16* a0 = A + (size_t)(bm + r0) * K + kc0;
  const u16* a1 = A + (size_t)(bm + 64 + r0) * K + kc0;
  const BT* b0 = B + (size_t)(bn + r0) * K + kc0;
  const BT* b1 = B + (size_t)(bn + 64 + r0) * K + kc0;
  u16* asd0 = &As[(size_t)tid * 8];
  u16* asd1 = &As[(size_t)(tid + 256) * 8];
  u16* bsd0 = &Bs[(size_t)tid * 8];
  u16* bsd1 = &Bs[(size_t)(tid + 256) * 8];

  for (int kt = 0; kt < K; kt += 32) {
    gload16(a0 + kt, asd0);
    gload16(a1 + kt, asd1);
    if constexpr (sizeof(BT) == 2) {
      gload16((const u16*)(b0 + kt), bsd0);
      gload16((const u16*)(b1 + kt), bsd1);
    } else {
      float4 x0 = *(const float4*)(b0 + kt);
      float4 x1 = *(const float4*)(b0 + kt + 4);
      float4 y0 = *(const float4*)(b1 + kt);
      float4 y1 = *(const float4*)(b1 + kt + 4);
      *(uint4*)bsd0 = make_uint4(pk2(x0.x, x0.y), pk2(x0.z, x0.w), pk2(x1.x, x1.y), pk2(x1.z, x1.w));
      *(uint4*)bsd1 = make_uint4(pk2(y0.x, y0.y), pk2(y0.z, y0.w), pk2(y1.x, y1.y), pk2(y1.z, y1.w));
    }
    __syncthreads();  // drains vmcnt+lgkmcnt -> LDS tiles valid
    bf16x8 af[4], bfr[4];
#pragma unroll
    for (int i = 0; i < 4; ++i) {
      af[i] = *(const bf16x8*)(&As[(wr + i * 16 + lo) * 32 + hi * 8]);
      bfr[i] = *(const bf16x8*)(&Bs[(wc + i * 16 + lo) * 32 + hi * 8]);
    }
#pragma unroll
    for (int i = 0; i < 4; ++i)
#pragma unroll
      for (int j = 0; j < 4; ++j) acc[i][j] = mfma_bf16(af[i], bfr[j], acc[i][j]);
    __syncthreads();  // protect LDS before next stage
  }

#pragma unroll
  for (int i = 0; i < 4; ++i) {
    const int gr = bm + wr + i * 16 + hi * 4;
#pragma unroll
    for (int j = 0; j < 4; ++j) {
      const int gc = bn + wc + j * 16 + lo;
#pragma unroll
      for (int r = 0; r < 4; ++r) {
        const size_t idx = (size_t)(gr + r) * N + gc;
        if constexpr (EPI == 1) {
          Cf[idx] = Res[idx] + acc[i][j][r];
        } else if constexpr (EPI == 2) {
          float g = bf2f(Cb[idx]);
          float s = g / (1.f + __expf(-g));
          Cb[idx] = f2bf(s * acc[i][j][r]);
        } else {
          Cb[idx] = f2bf(acc[i][j][r]);
        }
      }
    }
  }
}

// ---------------- V transpose: v[B,S,NH,HD] -> vt[B,NH,HD,S] ----------------
__global__ __launch_bounds__(256) void transpose_v(const u16* __restrict__ v,
                                                   u16* __restrict__ vt) {
  __shared__ u16 t[32][33];
  const int bh = blockIdx.z, b = bh >> 4, h = bh & 15;
  const int s0 = blockIdx.x * 32, d0 = blockIdx.y * 32;
  const int tx = threadIdx.x, ty = threadIdx.y;
#pragma unroll
  for (int i = 0; i < 4; ++i)
    t[ty + i * 8][tx] = v[(size_t)(b * 2048 + s0 + ty + i * 8) * 2048 + h * 128 + d0 + tx];
  __syncthreads();
#pragma unroll
  for (int i = 0; i < 4; ++i)
    vt[(size_t)(bh * 128 + d0 + ty + i * 8) * 2048 + s0 + tx] = t[tx][ty + i * 8];
}

// ---------------- flash attention fwd v2: LDS-staged K/V, double-buffered ----------------
// grid: (S/64, B*NH), block 256 = 4 waves x 16 q-rows.
// K tile [64][128] bf16 (256B rows), V tile [128][64] bf16 (128B rows), both
// XOR-swizzled (byte ^= (row&7)<<4) via pre-swizzled global_load_lds source
// (rule #21: linear dest + inverse-swz source + swz read).
// o may alias q: block reads only its own q rows (to regs) before writing them.
__global__ __launch_bounds__(256) void attn_fwd2(const u16* __restrict__ q,
                                                 const u16* __restrict__ k,
                                                 const u16* __restrict__ vt,
                                                 u16* o) {
  constexpr int S = 2048, HH = 2048;
  alignas(16) __shared__ u16 Ks[2][64 * 128];
  alignas(16) __shared__ u16 Vs[2][128 * 64];
  alignas(16) __shared__ u16 plds[4][16 * 72];
  const int bh = blockIdx.y, b = bh >> 4, h = bh & 15;
  const int tid = threadIdx.x, w = tid >> 6, lane = tid & 63;
  const int lo = lane & 15, hi = lane >> 4;
  const int qr = blockIdx.x * 64 + w * 16;
  u16* pl = &plds[w][0];

  bf16x8 qf[4];
  const u16* qb = q + (size_t)(b * S + qr + lo) * HH + h * 128 + hi * 8;
#pragma unroll
  for (int ks = 0; ks < 4; ++ks) qf[ks] = *(const bf16x8*)(qb + ks * 32);

  f32x4 oacc[8] = {};
  float m[4], l[4];
#pragma unroll
  for (int r = 0; r < 4; ++r) { m[r] = -1e30f; l[r] = 0.f; }

  const u16* kb = k + (size_t)(b * S) * HH + h * 128;  // K rows, stride HH
  const u16* vb = vt + (size_t)bh * 128 * S;           // Vt rows, stride S

  // pre-swizzled staging source columns (elements). LDS dest is linear:
  // K call c: LDS byte p = c*4096 + tid*16 -> row c*16+(tid>>4), col (tid&15)*16
  // V call c: LDS byte p = c*4096 + tid*16 -> row c*32+(tid>>3), col (tid&7)*16
  const int kcs = ((((tid & 15) * 16) ^ (((tid >> 4) & 7) << 4)) >> 1);
  const int vcs = ((((tid & 7) * 16) ^ (((tid >> 3) & 7) << 4)) >> 1);
  const u16* kgs = kb + (size_t)(tid >> 4) * HH + kcs;
  const u16* vgs = vb + (size_t)(tid >> 3) * S + vcs;

  int cur = 0;
  // prologue: stage tile 0
#pragma unroll
  for (int c = 0; c < 4; ++c) gload16(kgs + (size_t)(c * 16) * HH, &Ks[0][c * 2048 + tid * 8]);
#pragma unroll
  for (int c = 0; c < 4; ++c) gload16(vgs + (size_t)(c * 32) * S, &Vs[0][c * 2048 + tid * 8]);
  __syncthreads();

  const int swq = (lo & 7) << 4;  // row-swizzle byte for this lane's rows (row&7 == lo&7)

  for (int kv = 0; kv < S; kv += 64) {
    if (kv + 64 < S) {  // stage next tile into other buffer (hidden under compute)
      const int nb = cur ^ 1;
#pragma unroll
      for (int c = 0; c < 4; ++c)
        gload16(kgs + (size_t)(kv + 64 + c * 16) * HH, &Ks[nb][c * 2048 + tid * 8]);
#pragma unroll
      for (int c = 0; c < 4; ++c)
        gload16(vgs + (size_t)(c * 32) * S + kv + 64, &Vs[nb][c * 2048 + tid * 8]);
    }
    const u16* Kc = &Ks[cur][0];
    const u16* Vc = &Vs[cur][0];

    f32x4 sacc[4] = {};
    __builtin_amdgcn_s_setprio(1);
#pragma unroll
    for (int ks = 0; ks < 4; ++ks)
#pragma unroll
      for (int n = 0; n < 4; ++n) {
        bf16x8 kf = *(const bf16x8*)(Kc + (n * 16 + lo) * 128 + (((ks * 64 + hi * 16) ^ swq) >> 1));
        sacc[n] = mfma_bf16(qf[ks], kf, sacc[n]);
      }
    __builtin_amdgcn_s_setprio(0);

    constexpr float sc = 0.08838834764831845f;  // 1/sqrt(128)
    constexpr float L2E = 1.4426950408889634f;
#pragma unroll
    for (int n = 0; n < 4; ++n) sacc[n] = sacc[n] * sc;
    float mv[4];
#pragma unroll
    for (int r = 0; r < 4; ++r)
      mv[r] = fmaxf(fmaxf(sacc[0][r], sacc[1][r]), fmaxf(sacc[2][r], sacc[3][r]));
#pragma unroll
    for (int off = 1; off < 16; off <<= 1)
#pragma unroll
      for (int r = 0; r < 4; ++r) mv[r] = fmaxf(mv[r], __shfl_xor(mv[r], off));
    float corr[4];
#pragma unroll
    for (int r = 0; r < 4; ++r) {
      float mn = fmaxf(m[r], mv[r]);
      corr[r] = exp2f((m[r] - mn) * L2E);
      m[r] = mn;
    }
    f32x4 p[4];
#pragma unroll
    for (int n = 0; n < 4; ++n)
#pragma unroll
      for (int r = 0; r < 4; ++r) p[n][r] = exp2f((sacc[n][r] - m[r]) * L2E);
    float ps[4];
#pragma unroll
    for (int r = 0; r < 4; ++r) ps[r] = p[0][r] + p[1][r] + p[2][r] + p[3][r];
#pragma unroll
    for (int off = 1; off < 16; off <<= 1)
#pragma unroll
      for (int r = 0; r < 4; ++r) ps[r] += __shfl_xor(ps[r], off);
#pragma unroll
    for (int r = 0; r < 4; ++r) l[r] = l[r] * corr[r] + ps[r];
#pragma unroll
    for (int f = 0; f < 8; ++f)
#pragma unroll
      for (int r = 0; r < 4; ++r) oacc[f][r] *= corr[r];

    // P (16x64) -> padded LDS, reread as A-frags (within-wave only)
#pragma unroll
    for (int n = 0; n < 4; ++n)
#pragma unroll
      for (int r = 0; r < 4; ++r)
        pl[(hi * 4 + r) * 72 + n * 16 + lo] = f2bf(p[n][r]);
    asm volatile("s_waitcnt lgkmcnt(0)" ::: "memory");
    bf16x8 pf0 = *(const bf16x8*)(pl + lo * 72 + hi * 8);
    bf16x8 pf1 = *(const bf16x8*)(pl + lo * 72 + 32 + hi * 8);

    __builtin_amdgcn_s_setprio(1);
#pragma unroll
    for (int f = 0; f < 8; ++f) {
      const int row = f * 16 + lo;
      bf16x8 vf0 = *(const bf16x8*)(Vc + row * 64 + (((hi * 16) ^ swq) >> 1));
      bf16x8 vf1 = *(const bf16x8*)(Vc + row * 64 + (((64 + hi * 16) ^ swq) >> 1));
      oacc[f] = mfma_bf16(pf0, vf0, oacc[f]);
      oacc[f] = mfma_bf16(pf1, vf1, oacc[f]);
    }
    __builtin_amdgcn_s_setprio(0);

    __syncthreads();  // all waves done with cur; next buffer's DMA drained
    cur ^= 1;
  }

  u16* ob = o + (size_t)(b * S + qr) * HH + h * 128;
#pragma unroll
  for (int f = 0; f < 8; ++f)
#pragma unroll
    for (int r = 0; r < 4; ++r)
      ob[(size_t)(hi * 4 + r) * HH + f * 16 + lo] = f2bf(oacc[f][r] / l[r]);
}

// ---------------- host ----------------
extern "C" void kernel_launch(void* const* d_in, const int* in_sizes, int n_in,
                              void* d_out, int out_size, void* d_ws, size_t ws_size,
                              hipStream_t stream) {
  constexpr int B = 2, S = 2048, H = 2048, NH = 16, I = 8192;
  constexpr int M = B * S;   // 4096
  constexpr int MC = 2048;   // MLP M-chunk

  const float* hs = (const float*)d_in[0];
  const float* Wq = (const float*)d_in[1];
  const float* Wk = (const float*)d_in[2];
  const float* Wv = (const float*)d_in[3];
  const float* Wo = (const float*)d_in[4];
  const float* Wg = (const float*)d_in[5];
  const float* Wu = (const float*)d_in[6];
  const float* Wd = (const float*)d_in[7];
  const float* g_in = (const float*)d_in[8];
  const float* g_post = (const float*)d_in[9];
  float* out = (float*)d_out;

  constexpr size_t SZ_HH = (size_t)H * H * 2;  // 8 MiB
  constexpr size_t SZ_IH = (size_t)I * H * 2;  // 32 MiB
  constexpr size_t SZ_MH = (size_t)M * H * 2;  // 16 MiB
  constexpr size_t NEED_MIN = 5 * SZ_MH;                          // 80 MiB
  constexpr size_t NEED_FULL = NEED_MIN + 4 * SZ_HH + 3 * SZ_IH;  // 208 MiB

  char* p = (char*)d_ws;
  u16* x_b = (u16*)p;   p += SZ_MH;
  u16* q_b = (u16*)p;   p += SZ_MH;   // also attention output (in-place)
  u16* k_b = (u16*)p;   p += SZ_MH;
  u16* v_b = (u16*)p;   p += SZ_MH;
  u16* vt_b = (u16*)p;  p += SZ_MH;
  u16* g_mlp = k_b;  // 32 MiB gate chunk reuses dead K+V after attention
  const bool fast = ws_size >= NEED_FULL;
  u16 *wq_b = nullptr, *wk_b = nullptr, *wv_b = nullptr, *wo_b = nullptr,
      *wg_b = nullptr, *wu_b = nullptr, *wd_b = nullptr;
  if (fast) {
    wq_b = (u16*)p; p += SZ_HH;
    wk_b = (u16*)p; p += SZ_HH;
    wv_b = (u16*)p; p += SZ_HH;
    wo_b = (u16*)p; p += SZ_HH;
    wg_b = (u16*)p; p += SZ_IH;
    wu_b = (u16*)p; p += SZ_IH;
    wd_b = (u16*)p; p += SZ_IH;
    cvt_bf16<<<1024, 256, 0, stream>>>(Wq, wq_b, H * H / 8);
    cvt_bf16<<<1024, 256, 0, stream>>>(Wk, wk_b, H * H / 8);
    cvt_bf16<<<1024, 256, 0, stream>>>(Wv, wv_b, H * H / 8);
    cvt_bf16<<<1024, 256, 0, stream>>>(Wo, wo_b, H * H / 8);
    cvt_bf16<<<1024, 256, 0, stream>>>(Wg, wg_b, I * H / 8);
    cvt_bf16<<<1024, 256, 0, stream>>>(Wu, wu_b, I * H / 8);
    cvt_bf16<<<1024, 256, 0, stream>>>(Wd, wd_b, I * H / 8);
  }

  // x = rmsnorm(hidden, g_in)
  rmsnorm_bf16<<<M, 256, 0, stream>>>(hs, g_in, x_b);

  // Q/K/V projections
  const dim3 gHH(H / 128, M / 128);
  if (fast) {
    gemm_bt<0, u16><<<gHH, 256, 0, stream>>>(x_b, wq_b, q_b, nullptr, nullptr, M, H, H);
    gemm_bt<0, u16><<<gHH, 256, 0, stream>>>(x_b, wk_b, k_b, nullptr, nullptr, M, H, H);
    gemm_bt<0, u16><<<gHH, 256, 0, stream>>>(x_b, wv_b, v_b, nullptr, nullptr, M, H, H);
  } else {
    gemm_bt<0, float><<<gHH, 256, 0, stream>>>(x_b, Wq, q_b, nullptr, nullptr, M, H, H);
    gemm_bt<0, float><<<gHH, 256, 0, stream>>>(x_b, Wk, k_b, nullptr, nullptr, M, H, H);
    gemm_bt<0, float><<<gHH, 256, 0, stream>>>(x_b, Wv, v_b, nullptr, nullptr, M, H, H);
  }

  // V -> Vt per head, then attention (output in-place into q_b)
  transpose_v<<<dim3(S / 32, 128 / 32, B * NH), dim3(32, 8), 0, stream>>>(v_b, vt_b);
  attn_fwd2<<<dim3(S / 64, B * NH), 256, 0, stream>>>(q_b, k_b, vt_b, q_b);

  // hidden2 = residual + attn @ Wo^T   (fp32, into d_out)
  if (fast)
    gemm_bt<1, u16><<<gHH, 256, 0, stream>>>(q_b, wo_b, nullptr, out, hs, M, H, H);
  else
    gemm_bt<1, float><<<gHH, 256, 0, stream>>>(q_b, Wo, nullptr, out, hs, M, H, H);

  // x2 = rmsnorm(hidden2, g_post)
  rmsnorm_bf16<<<M, 256, 0, stream>>>(out, g_post, x_b);

  // MLP, chunked over M so gate fits in 32 MiB
  const dim3 gIH(I / 128, MC / 128), gHI(H / 128, MC / 128);
  for (int mc = 0; mc < M / MC; ++mc) {
    const u16* xc = x_b + (size_t)mc * MC * H;
    float* oc = out + (size_t)mc * MC * H;
    if (fast) {
      gemm_bt<0, u16><<<gIH, 256, 0, stream>>>(xc, wg_b, g_mlp, nullptr, nullptr, MC, I, H);
      gemm_bt<2, u16><<<gIH, 256, 0, stream>>>(xc, wu_b, g_mlp, nullptr, nullptr, MC, I, H);
      gemm_bt<1, u16><<<gHI, 256, 0, stream>>>(g_mlp, wd_b, nullptr, oc, oc, MC, H, I);
    } else {
      gemm_bt<0, float><<<gIH, 256, 0, stream>>>(xc, Wg, g_mlp, nullptr, nullptr, MC, I, H);
      gemm_bt<2, float><<<gIH, 256, 0, stream>>>(xc, Wu, g_mlp, nullptr, nullptr, MC, I, H);
      gemm_bt<1, float><<<gHI, 256, 0, stream>>>(g_mlp, Wd, nullptr, oc, oc, MC, H, I);
    }
  }
}

// Round 5
// 871.014 us; speedup vs baseline: 1.9886x; 1.5963x over previous
//
#include <hip/hip_runtime.h>

using u16 = unsigned short;
using u32 = unsigned int;

typedef __attribute__((ext_vector_type(8))) __bf16 bf16x8;
typedef __attribute__((ext_vector_type(4))) float f32x4;

__device__ __forceinline__ u16 f2bf(float f) {
  u32 u = __float_as_uint(f);
  u32 r = (u + 0x7fffu + ((u >> 16) & 1u)) >> 16;  // RNE
  return (u16)r;
}
__device__ __forceinline__ u32 pk2(float a, float b) {
  return (u32)f2bf(a) | ((u32)f2bf(b) << 16);
}
__device__ __forceinline__ float bf2f(u16 h) {
  return __uint_as_float(((u32)h) << 16);
}
__device__ __forceinline__ void gload16(const u16* g, u16* l) {
  __builtin_amdgcn_global_load_lds((const __attribute__((address_space(1))) void*)g,
                                   (__attribute__((address_space(3))) void*)l, 16, 0, 0);
}
__device__ __forceinline__ f32x4 mfma_bf16(bf16x8 a, bf16x8 b, f32x4 c) {
  return __builtin_amdgcn_mfma_f32_16x16x32_bf16(a, b, c, 0, 0, 0);
}

// ---------------- fp32 -> bf16 convert ----------------
__global__ __launch_bounds__(256) void cvt_bf16(const float* __restrict__ in,
                                                u16* __restrict__ out, int n8) {
  int i = blockIdx.x * 256 + threadIdx.x;
  int stride = gridDim.x * 256;
  for (; i < n8; i += stride) {
    float4 a = ((const float4*)in)[(size_t)i * 2];
    float4 b = ((const float4*)in)[(size_t)i * 2 + 1];
    ((uint4*)out)[i] = make_uint4(pk2(a.x, a.y), pk2(a.z, a.w), pk2(b.x, b.y), pk2(b.z, b.w));
  }
}

// ---------------- RMSNorm (H=2048), fp32 in -> bf16 out ----------------
__global__ __launch_bounds__(256) void rmsnorm_bf16(const float* __restrict__ x,
                                                    const float* __restrict__ g,
                                                    u16* __restrict__ o) {
  const int row = blockIdx.x;
  const int tid = threadIdx.x;
  const float4* xr = (const float4*)(x + (size_t)row * 2048);
  float4 a = xr[tid * 2], b = xr[tid * 2 + 1];
  float s = a.x * a.x + a.y * a.y + a.z * a.z + a.w * a.w +
            b.x * b.x + b.y * b.y + b.z * b.z + b.w * b.w;
#pragma unroll
  for (int off = 1; off < 64; off <<= 1) s += __shfl_xor(s, off);
  __shared__ float red[4];
  if ((tid & 63) == 0) red[tid >> 6] = s;
  __syncthreads();
  s = red[0] + red[1] + red[2] + red[3];
  const float r = rsqrtf(s * (1.0f / 2048.0f) + 1.1920929e-07f);
  const float4* gr = (const float4*)g;
  float4 ga = gr[tid * 2], gb = gr[tid * 2 + 1];
  ((uint4*)(o + (size_t)row * 2048))[tid] =
      make_uint4(pk2(a.x * r * ga.x, a.y * r * ga.y), pk2(a.z * r * ga.z, a.w * r * ga.w),
                 pk2(b.x * r * gb.x, b.y * r * gb.y), pk2(b.z * r * gb.z, b.w * r * gb.w));
}

// ================= 256x{256,128} tile GEMM, 8 waves, BK=64, 2-phase =================
// C[M,N] = A[M,K](row stride lda) @ B[N,K]^T (+ epilogue).
// EPI=0: Cb=bf16(acc). EPI=1: Cf=Res+acc (fp32, may alias). EPI=2: Cb=bf16(silu(Cb)*acc).
// LDS halves [128][64] bf16, window swizzle: phys_win = log_win ^ (row&7), applied on
// write via pre-swizzled global source (linear LDS dest for global_load_lds) and on read.
template <int EPI, int BN, int WM, int WN>
__global__ __launch_bounds__(512, 2) void gemm256(const u16* __restrict__ A,
                                                  const u16* __restrict__ B,
                                                  u16* Cb, float* Cf, const float* __restrict__ Res,
                                                  int M, int N, int K, int lda) {
  constexpr int NBH = BN / 128;      // B halves per tile
  constexpr int MR = 256 / WM / 16;  // A frags per wave
  constexpr int NR = BN / WN / 16;   // B frags per wave
  constexpr int HALF = 8192;         // u16 per 16KB half
  alignas(16) __shared__ u16 lds[2][(2 + NBH) * HALF];

  const int tid = threadIdx.x;
  const int w = tid >> 6, lane = tid & 63;
  const int lo = lane & 15, hi = lane >> 4;

  // XCD-aware block swizzle (grid % 8 == 0 for all launches)
  const int nwg = gridDim.x;
  const int swz = (blockIdx.x & 7) * (nwg >> 3) + (blockIdx.x >> 3);
  const int nbx = N / BN;
  const int bm = (swz / nbx) * 256, bn = (swz % nbx) * BN;

  const int wm = w / WN, wn = w % WN;
  const int WRB = wm * (256 / WM), WCB = wn * (BN / WN);
  const int ah = WRB >> 7, arb = WRB & 127;
  const int bh = WCB >> 7, brb = WCB & 127;

  // staging: thread t covers row (t>>3) of each 64-row slab, 16B window (t&7).
  // phys window (t&7) at row r must hold logical window (t&7)^(r&7); r&7 == (t>>3)&7.
  const int trow = tid >> 3, twin = tid & 7;
  const int scol = (twin ^ (trow & 7)) * 8;  // element offset of the 16B chunk to fetch
  const u16* Ag = A + (size_t)(bm + trow) * lda + scol;
  const u16* Bg = B + (size_t)(bn + trow) * K + scol;

  f32x4 acc[MR][NR] = {};

#define STAGE(Ld, kt)                                                              \
  {                                                                                \
    _Pragma("unroll") for (int hc = 0; hc < 4; ++hc)                               \
        gload16(Ag + (size_t)(hc * 64) * lda + (kt), (Ld) + hc * 4096 + tid * 8);  \
    _Pragma("unroll") for (int hc = 0; hc < NBH * 2; ++hc)                         \
        gload16(Bg + (size_t)(hc * 64) * K + (kt), (Ld) + (2 + 0) * HALF + hc * 4096 + tid * 8); \
  }

  STAGE(&lds[0][0], 0);
  __syncthreads();
  int cur = 0;
  for (int kt = 0; kt < K; kt += 64) {
    if (kt + 64 < K) STAGE(&lds[cur ^ 1][0], kt + 64);
    const u16* LA = &lds[cur][0] + ah * HALF;
    const u16* LB = &lds[cur][0] + (2 + bh) * HALF;
#pragma unroll
    for (int ks = 0; ks < 2; ++ks) {
      const int pw = ((ks << 2) | hi) ^ (lo & 7);  // swizzled 16B window
      bf16x8 af[MR], bf[NR];
#pragma unroll
      for (int m = 0; m < MR; ++m)
        af[m] = *(const bf16x8*)(LA + (arb + m * 16 + lo) * 64 + pw * 8);
#pragma unroll
      for (int n = 0; n < NR; ++n)
        bf[n] = *(const bf16x8*)(LB + (brb + n * 16 + lo) * 64 + pw * 8);
      __builtin_amdgcn_s_setprio(1);
#pragma unroll
      for (int m = 0; m < MR; ++m)
#pragma unroll
        for (int n = 0; n < NR; ++n) acc[m][n] = mfma_bf16(af[m], bf[n], acc[m][n]);
      __builtin_amdgcn_s_setprio(0);
    }
    __syncthreads();  // drains this tile's prefetch DMA; frees cur for next stage
    cur ^= 1;
  }
#undef STAGE

#pragma unroll
  for (int m = 0; m < MR; ++m) {
    const int gr = bm + WRB + m * 16 + hi * 4;
#pragma unroll
    for (int n = 0; n < NR; ++n) {
      const int gc = bn + WCB + n * 16 + lo;
#pragma unroll
      for (int r = 0; r < 4; ++r) {
        const size_t idx = (size_t)(gr + r) * N + gc;
        if constexpr (EPI == 1) {
          Cf[idx] = Res[idx] + acc[m][n][r];
        } else if constexpr (EPI == 2) {
          float g = bf2f(Cb[idx]);
          float s = g / (1.f + __expf(-g));
          Cb[idx] = f2bf(s * acc[m][n][r]);
        } else {
          Cb[idx] = f2bf(acc[m][n][r]);
        }
      }
    }
  }
}

// ---------------- old 128^2 GEMM (fallback tier), fp32 B on the fly ----------------
template <int EPI>
__global__ __launch_bounds__(256) void gemm_bt(const u16* __restrict__ A,
                                               const float* __restrict__ B,
                                               u16* Cb, float* Cf, const float* Res,
                                               int M, int N, int K) {
  alignas(16) __shared__ u16 As[128 * 32];
  alignas(16) __shared__ u16 Bs[128 * 32];
  const int tid = threadIdx.x;
  const int w = tid >> 6, lane = tid & 63;
  const int lo = lane & 15, hi = lane >> 4;
  const int bm = blockIdx.y * 128, bn = blockIdx.x * 128;
  const int wr = (w >> 1) * 64, wc = (w & 1) * 64;
  f32x4 acc[4][4] = {};
  const int r0 = tid >> 2, kc0 = (tid & 3) * 8;
  const u16* a0 = A + (size_t)(bm + r0) * K + kc0;
  const u16* a1 = A + (size_t)(bm + 64 + r0) * K + kc0;
  const float* b0 = B + (size_t)(bn + r0) * K + kc0;
  const float* b1 = B + (size_t)(bn + 64 + r0) * K + kc0;
  u16* asd0 = &As[(size_t)tid * 8];
  u16* asd1 = &As[(size_t)(tid + 256) * 8];
  u16* bsd0 = &Bs[(size_t)tid * 8];
  u16* bsd1 = &Bs[(size_t)(tid + 256) * 8];
  for (int kt = 0; kt < K; kt += 32) {
    gload16(a0 + kt, asd0);
    gload16(a1 + kt, asd1);
    float4 x0 = *(const float4*)(b0 + kt);
    float4 x1 = *(const float4*)(b0 + kt + 4);
    float4 y0 = *(const float4*)(b1 + kt);
    float4 y1 = *(const float4*)(b1 + kt + 4);
    *(uint4*)bsd0 = make_uint4(pk2(x0.x, x0.y), pk2(x0.z, x0.w), pk2(x1.x, x1.y), pk2(x1.z, x1.w));
    *(uint4*)bsd1 = make_uint4(pk2(y0.x, y0.y), pk2(y0.z, y0.w), pk2(y1.x, y1.y), pk2(y1.z, y1.w));
    __syncthreads();
    bf16x8 af[4], bfr[4];
#pragma unroll
    for (int i = 0; i < 4; ++i) {
      af[i] = *(const bf16x8*)(&As[(wr + i * 16 + lo) * 32 + hi * 8]);
      bfr[i] = *(const bf16x8*)(&Bs[(wc + i * 16 + lo) * 32 + hi * 8]);
    }
#pragma unroll
    for (int i = 0; i < 4; ++i)
#pragma unroll
      for (int j = 0; j < 4; ++j) acc[i][j] = mfma_bf16(af[i], bfr[j], acc[i][j]);
    __syncthreads();
  }
#pragma unroll
  for (int i = 0; i < 4; ++i) {
    const int gr = bm + wr + i * 16 + hi * 4;
#pragma unroll
    for (int j = 0; j < 4; ++j) {
      const int gc = bn + wc + j * 16 + lo;
#pragma unroll
      for (int r = 0; r < 4; ++r) {
        const size_t idx = (size_t)(gr + r) * N + gc;
        if constexpr (EPI == 1) {
          Cf[idx] = Res[idx] + acc[i][j][r];
        } else if constexpr (EPI == 2) {
          float g = bf2f(Cb[idx]);
          float s = g / (1.f + __expf(-g));
          Cb[idx] = f2bf(s * acc[i][j][r]);
        } else {
          Cb[idx] = f2bf(acc[i][j][r]);
        }
      }
    }
  }
}

// ---------------- V transpose: v rows (stride ldv) -> vt[bh*128+d][S] ----------------
__global__ __launch_bounds__(256) void transpose_v(const u16* __restrict__ v,
                                                   u16* __restrict__ vt, int ldv) {
  __shared__ u16 t[32][33];
  const int bh = blockIdx.z, b = bh >> 4, h = bh & 15;
  const int s0 = blockIdx.x * 32, d0 = blockIdx.y * 32;
  const int tx = threadIdx.x, ty = threadIdx.y;
#pragma unroll
  for (int i = 0; i < 4; ++i)
    t[ty + i * 8][tx] = v[(size_t)(b * 2048 + s0 + ty + i * 8) * ldv + h * 128 + d0 + tx];
  __syncthreads();
#pragma unroll
  for (int i = 0; i < 4; ++i)
    vt[(size_t)(bh * 128 + d0 + ty + i * 8) * 2048 + s0 + tx] = t[tx][ty + i * 8];
}

// ---------------- flash attention fwd: LDS-staged K/V, double-buffered ----------------
// q/k/o rows have stride ldq (supports fused-QKV layout). o may alias q.
__global__ __launch_bounds__(256) void attn_fwd2(const u16* __restrict__ q,
                                                 const u16* __restrict__ k,
                                                 const u16* __restrict__ vt,
                                                 u16* o, int ldq) {
  constexpr int S = 2048;
  alignas(16) __shared__ u16 Ks[2][64 * 128];
  alignas(16) __shared__ u16 Vs[2][128 * 64];
  alignas(16) __shared__ u16 plds[4][16 * 72];
  const int bh = blockIdx.y, b = bh >> 4, h = bh & 15;
  const int tid = threadIdx.x, w = tid >> 6, lane = tid & 63;
  const int lo = lane & 15, hi = lane >> 4;
  const int qr = blockIdx.x * 64 + w * 16;
  u16* pl = &plds[w][0];

  bf16x8 qf[4];
  const u16* qb = q + (size_t)(b * S + qr + lo) * ldq + h * 128 + hi * 8;
#pragma unroll
  for (int ks = 0; ks < 4; ++ks) qf[ks] = *(const bf16x8*)(qb + ks * 32);

  f32x4 oacc[8] = {};
  float m[4], l[4];
#pragma unroll
  for (int r = 0; r < 4; ++r) { m[r] = -1e30f; l[r] = 0.f; }

  const u16* kb = k + (size_t)(b * S) * ldq + h * 128;
  const u16* vb = vt + (size_t)bh * 128 * S;

  const int kcs = ((((tid & 15) * 16) ^ (((tid >> 4) & 7) << 4)) >> 1);
  const int vcs = ((((tid & 7) * 16) ^ (((tid >> 3) & 7) << 4)) >> 1);
  const u16* kgs = kb + (size_t)(tid >> 4) * ldq + kcs;
  const u16* vgs = vb + (size_t)(tid >> 3) * S + vcs;

  int cur = 0;
#pragma unroll
  for (int c = 0; c < 4; ++c) gload16(kgs + (size_t)(c * 16) * ldq, &Ks[0][c * 2048 + tid * 8]);
#pragma unroll
  for (int c = 0; c < 4; ++c) gload16(vgs + (size_t)(c * 32) * S, &Vs[0][c * 2048 + tid * 8]);
  __syncthreads();

  const int swq = (lo & 7) << 4;

  for (int kv = 0; kv < S; kv += 64) {
    if (kv + 64 < S) {
      const int nb = cur ^ 1;
#pragma unroll
      for (int c = 0; c < 4; ++c)
        gload16(kgs + (size_t)(kv + 64 + c * 16) * ldq, &Ks[nb][c * 2048 + tid * 8]);
#pragma unroll
      for (int c = 0; c < 4; ++c)
        gload16(vgs + (size_t)(c * 32) * S + kv + 64, &Vs[nb][c * 2048 + tid * 8]);
    }
    const u16* Kc = &Ks[cur][0];
    const u16* Vc = &Vs[cur][0];

    f32x4 sacc[4] = {};
    __builtin_amdgcn_s_setprio(1);
#pragma unroll
    for (int ks = 0; ks < 4; ++ks)
#pragma unroll
      for (int n = 0; n < 4; ++n) {
        bf16x8 kf = *(const bf16x8*)(Kc + (n * 16 + lo) * 128 + (((ks * 64 + hi * 16) ^ swq) >> 1));
        sacc[n] = mfma_bf16(qf[ks], kf, sacc[n]);
      }
    __builtin_amdgcn_s_setprio(0);

    constexpr float sc = 0.08838834764831845f;
    constexpr float L2E = 1.4426950408889634f;
#pragma unroll
    for (int n = 0; n < 4; ++n) sacc[n] = sacc[n] * sc;
    float mv[4];
#pragma unroll
    for (int r = 0; r < 4; ++r)
      mv[r] = fmaxf(fmaxf(sacc[0][r], sacc[1][r]), fmaxf(sacc[2][r], sacc[3][r]));
#pragma unroll
    for (int off = 1; off < 16; off <<= 1)
#pragma unroll
      for (int r = 0; r < 4; ++r) mv[r] = fmaxf(mv[r], __shfl_xor(mv[r], off));
    float corr[4];
#pragma unroll
    for (int r = 0; r < 4; ++r) {
      float mn = fmaxf(m[r], mv[r]);
      corr[r] = exp2f((m[r] - mn) * L2E);
      m[r] = mn;
    }
    f32x4 p[4];
#pragma unroll
    for (int n = 0; n < 4; ++n)
#pragma unroll
      for (int r = 0; r < 4; ++r) p[n][r] = exp2f((sacc[n][r] - m[r]) * L2E);
    float ps[4];
#pragma unroll
    for (int r = 0; r < 4; ++r) ps[r] = p[0][r] + p[1][r] + p[2][r] + p[3][r];
#pragma unroll
    for (int off = 1; off < 16; off <<= 1)
#pragma unroll
      for (int r = 0; r < 4; ++r) ps[r] += __shfl_xor(ps[r], off);
#pragma unroll
    for (int r = 0; r < 4; ++r) l[r] = l[r] * corr[r] + ps[r];
#pragma unroll
    for (int f = 0; f < 8; ++f)
#pragma unroll
      for (int r = 0; r < 4; ++r) oacc[f][r] *= corr[r];

#pragma unroll
    for (int n = 0; n < 4; ++n)
#pragma unroll
      for (int r = 0; r < 4; ++r)
        pl[(hi * 4 + r) * 72 + n * 16 + lo] = f2bf(p[n][r]);
    asm volatile("s_waitcnt lgkmcnt(0)" ::: "memory");
    bf16x8 pf0 = *(const bf16x8*)(pl + lo * 72 + hi * 8);
    bf16x8 pf1 = *(const bf16x8*)(pl + lo * 72 + 32 + hi * 8);

    __builtin_amdgcn_s_setprio(1);
#pragma unroll
    for (int f = 0; f < 8; ++f) {
      const int row = f * 16 + lo;
      bf16x8 vf0 = *(const bf16x8*)(Vc + row * 64 + (((hi * 16) ^ swq) >> 1));
      bf16x8 vf1 = *(const bf16x8*)(Vc + row * 64 + (((64 + hi * 16) ^ swq) >> 1));
      oacc[f] = mfma_bf16(pf0, vf0, oacc[f]);
      oacc[f] = mfma_bf16(pf1, vf1, oacc[f]);
    }
    __builtin_amdgcn_s_setprio(0);

    __syncthreads();
    cur ^= 1;
  }

  u16* ob = o + (size_t)(b * S + qr) * ldq + h * 128;
#pragma unroll
  for (int f = 0; f < 8; ++f)
#pragma unroll
    for (int r = 0; r < 4; ++r)
      ob[(size_t)(hi * 4 + r) * ldq + f * 16 + lo] = f2bf(oacc[f][r] / l[r]);
}

// ---------------- host ----------------
extern "C" void kernel_launch(void* const* d_in, const int* in_sizes, int n_in,
                              void* d_out, int out_size, void* d_ws, size_t ws_size,
                              hipStream_t stream) {
  constexpr int B = 2, S = 2048, H = 2048, NH = 16, I = 8192;
  constexpr int M = B * S;  // 4096

  const float* hs = (const float*)d_in[0];
  const float* Wq = (const float*)d_in[1];
  const float* Wk = (const float*)d_in[2];
  const float* Wv = (const float*)d_in[3];
  const float* Wo = (const float*)d_in[4];
  const float* Wg = (const float*)d_in[5];
  const float* Wu = (const float*)d_in[6];
  const float* Wd = (const float*)d_in[7];
  const float* g_in = (const float*)d_in[8];
  const float* g_post = (const float*)d_in[9];
  float* out = (float*)d_out;

  constexpr size_t SZ_HH = (size_t)H * H * 2;   // 8 MiB
  constexpr size_t SZ_IH = (size_t)I * H * 2;   // 32 MiB
  constexpr size_t SZ_MH = (size_t)M * H * 2;   // 16 MiB
  constexpr size_t NEED_NEW = SZ_MH + 3 * SZ_MH + SZ_MH + SZ_IH;  // x + qkv + vt + wsc = 112 MiB

  if (ws_size >= NEED_NEW) {
    char* p = (char*)d_ws;
    u16* x_b = (u16*)p;    p += SZ_MH;       // [4096][2048]
    u16* qkv_b = (u16*)p;  p += 3 * SZ_MH;   // [4096][6144]  (q|k|v)
    u16* vt_b = (u16*)p;   p += SZ_MH;       // [B*NH*128][2048]
    u16* wsc = (u16*)p;    p += SZ_IH;       // weight scratch, 32 MiB
    u16* gate_b = qkv_b;                     // [4096][8192] overlays qkv+vt after attn

    // x = rmsnorm(hidden, g_in)
    rmsnorm_bf16<<<M, 256, 0, stream>>>(hs, g_in, x_b);

    // fused QKV: W = [Wq;Wk;Wv] -> wsc [6144][2048]
    cvt_bf16<<<1024, 256, 0, stream>>>(Wq, wsc, H * H / 8);
    cvt_bf16<<<1024, 256, 0, stream>>>(Wk, wsc + (size_t)H * H, H * H / 8);
    cvt_bf16<<<1024, 256, 0, stream>>>(Wv, wsc + (size_t)2 * H * H, H * H / 8);
    gemm256<0, 256, 2, 4><<<(M / 256) * (3 * H / 256), 512, 0, stream>>>(
        x_b, wsc, qkv_b, nullptr, nullptr, M, 3 * H, H, H);

    // V -> Vt, attention in-place into q-slice
    transpose_v<<<dim3(S / 32, 128 / 32, B * NH), dim3(32, 8), 0, stream>>>(
        qkv_b + 2 * H, vt_b, 3 * H);
    attn_fwd2<<<dim3(S / 64, B * NH), 256, 0, stream>>>(qkv_b, qkv_b + H, vt_b, qkv_b, 3 * H);

    // hidden2 = residual + attn @ Wo^T
    cvt_bf16<<<1024, 256, 0, stream>>>(Wo, wsc, H * H / 8);
    gemm256<1, 128, 4, 2><<<(M / 256) * (H / 128), 512, 0, stream>>>(
        qkv_b, wsc, nullptr, out, hs, M, H, H, 3 * H);

    // x2 = rmsnorm(hidden2, g_post)
    rmsnorm_bf16<<<M, 256, 0, stream>>>(out, g_post, x_b);

    // MLP (unchunked): gate = x2 @ Wg^T ; gate = silu(gate)*(x2 @ Wu^T) ; out += gate @ Wd^T
    cvt_bf16<<<1024, 256, 0, stream>>>(Wg, wsc, I * H / 8);
    gemm256<0, 256, 2, 4><<<(M / 256) * (I / 256), 512, 0, stream>>>(
        x_b, wsc, gate_b, nullptr, nullptr, M, I, H, H);
    cvt_bf16<<<1024, 256, 0, stream>>>(Wu, wsc, I * H / 8);
    gemm256<2, 256, 2, 4><<<(M / 256) * (I / 256), 512, 0, stream>>>(
        x_b, wsc, gate_b, nullptr, nullptr, M, I, H, H);
    cvt_bf16<<<1024, 256, 0, stream>>>(Wd, wsc, I * H / 8);
    gemm256<1, 128, 4, 2><<<(M / 256) * (H / 128), 512, 0, stream>>>(
        gate_b, wsc, nullptr, out, out, M, H, I, I);
    return;
  }

  // ---------- fallback tier (ws >= 80 MiB): old 128^2 path, fp32 B on the fly ----------
  constexpr int MC = 2048;
  char* p = (char*)d_ws;
  u16* x_b = (u16*)p;   p += SZ_MH;
  u16* q_b = (u16*)p;   p += SZ_MH;
  u16* k_b = (u16*)p;   p += SZ_MH;
  u16* v_b = (u16*)p;   p += SZ_MH;
  u16* vt_b = (u16*)p;  p += SZ_MH;
  u16* g_mlp = k_b;

  rmsnorm_bf16<<<M, 256, 0, stream>>>(hs, g_in, x_b);
  const dim3 gHH(H / 128, M / 128);
  gemm_bt<0><<<gHH, 256, 0, stream>>>(x_b, Wq, q_b, nullptr, nullptr, M, H, H);
  gemm_bt<0><<<gHH, 256, 0, stream>>>(x_b, Wk, k_b, nullptr, nullptr, M, H, H);
  gemm_bt<0><<<gHH, 256, 0, stream>>>(x_b, Wv, v_b, nullptr, nullptr, M, H, H);
  transpose_v<<<dim3(S / 32, 128 / 32, B * NH), dim3(32, 8), 0, stream>>>(v_b, vt_b, H);
  attn_fwd2<<<dim3(S / 64, B * NH), 256, 0, stream>>>(q_b, k_b, vt_b, q_b, H);
  gemm_bt<1><<<gHH, 256, 0, stream>>>(q_b, Wo, nullptr, out, hs, M, H, H);
  rmsnorm_bf16<<<M, 256, 0, stream>>>(out, g_post, x_b);
  const dim3 gIH(I / 128, MC / 128), gHI(H / 128, MC / 128);
  for (int mc = 0; mc < M / MC; ++mc) {
    const u16* xc = x_b + (size_t)mc * MC * H;
    float* oc = out + (size_t)mc * MC * H;
    gemm_bt<0><<<gIH, 256, 0, stream>>>(xc, Wg, g_mlp, nullptr, nullptr, MC, I, H);
    gemm_bt<2><<<gIH, 256, 0, stream>>>(xc, Wu, g_mlp, nullptr, nullptr, MC, I, H);
    gemm_bt<1><<<gHI, 256, 0, stream>>>(g_mlp, Wd, nullptr, oc, oc, MC, H, I);
  }
}